// Round 2
// baseline (60.105 us; speedup 1.0000x reference)
//
#include <hip/hip_runtime.h>
#include <hip/hip_bf16.h>

typedef __bf16 v8bf __attribute__((ext_vector_type(8)));
typedef float f32x16 __attribute__((ext_vector_type(16)));
typedef unsigned int uint;
typedef unsigned short ushort;

__device__ inline f32x16 zero16() {
  f32x16 z;
#pragma unroll
  for (int i = 0; i < 16; i++) z[i] = 0.f;
  return z;
}

__device__ inline uint pack_bf16(float a, float b) {
  union { __bf16 h[2]; uint u; } c;
  c.h[0] = (__bf16)a;
  c.h[1] = (__bf16)b;
  return c.u;
}

// ---------------------------------------------------------------------------
// Kernel 0: build Wt[192][1024] bf16, rows 0-63 = Wq cols, 64-127 = Wk, 128-191 = Wv
// ---------------------------------------------------------------------------
__global__ void prep_wt(const float* __restrict__ Wq, const float* __restrict__ Wk,
                        const float* __restrict__ Wv, __bf16* __restrict__ Wt) {
  int n = blockIdx.x;  // 0..191
  const float* src = (n < 64) ? Wq : (n < 128) ? Wk : Wv;
  int h = n & 63;
  for (int c = threadIdx.x; c < 1024; c += blockDim.x) {
    Wt[n * 1024 + c] = (__bf16)src[c * 64 + h];
  }
}

// ---------------------------------------------------------------------------
// Kernel 1: KQV[32768][192] = x[32768][1024] * W  (bf16 MFMA, fp32 accum)
// 256 blocks x 512 threads; block tile 128x192, wave tile 32x96, BK=64
// ---------------------------------------------------------------------------
__launch_bounds__(512, 2)
__global__ void proj_kernel(const float* __restrict__ x, const uint4* __restrict__ Wt4,
                            __bf16* __restrict__ KQV) {
  __shared__ uint4 lds4[40960 / 16];  // A: [128][64]bf16 swz (16KB), W: [192][64] (24KB)
  char* Alds = (char*)lds4;
  char* Wlds = (char*)lds4 + 16384;

  const int tid = threadIdx.x;
  const int lane = tid & 63;
  const int wave = tid >> 6;  // 0..7
  const int wm = wave >> 1;   // 0..3 (M)
  const int wn = wave & 1;    // 0..1 (N)
  const int row0 = blockIdx.x * 128;

  f32x16 acc[3];
#pragma unroll
  for (int i = 0; i < 3; i++) acc[i] = zero16();

  for (int k0 = 0; k0 < 1024; k0 += 64) {
    // stage A tile: 128 rows x 64 cols, fp32 -> bf16, 1024 16B chunks / 512 thr
#pragma unroll
    for (int i = 0; i < 2; i++) {
      int c = tid + i * 512;
      int r = c >> 3, cc = c & 7;
      const float4* src = (const float4*)(x + (size_t)(row0 + r) * 1024 + k0 + cc * 8);
      float4 f0 = src[0], f1 = src[1];
      union { __bf16 h[8]; v8bf v; } cv;
      cv.h[0] = (__bf16)f0.x; cv.h[1] = (__bf16)f0.y;
      cv.h[2] = (__bf16)f0.z; cv.h[3] = (__bf16)f0.w;
      cv.h[4] = (__bf16)f1.x; cv.h[5] = (__bf16)f1.y;
      cv.h[6] = (__bf16)f1.z; cv.h[7] = (__bf16)f1.w;
      int byte = r * 128 + ((cc * 16) ^ ((r & 7) << 4));
      *(v8bf*)(Alds + byte) = cv.v;
    }
    // stage W tile (already bf16): 192 rows x 64 k, 1536 chunks / 512 thr
#pragma unroll
    for (int i = 0; i < 3; i++) {
      int c = tid + i * 512;
      int n = c >> 3, cc = c & 7;
      uint4 w = Wt4[n * 128 + (k0 >> 3) + cc];
      int byte = n * 128 + ((cc * 16) ^ ((n & 7) << 4));
      *(uint4*)(Wlds + byte) = w;
    }
    __syncthreads();
    // compute: 4 k-subtiles of 16
#pragma unroll
    for (int ks = 0; ks < 4; ks++) {
      int kbyte = ks * 32 + ((lane >> 5) << 4);
      int arow = wm * 32 + (lane & 31);
      v8bf a = *(const v8bf*)(Alds + arow * 128 + (kbyte ^ ((arow & 7) << 4)));
#pragma unroll
      for (int nf = 0; nf < 3; nf++) {
        int brow = wn * 96 + nf * 32 + (lane & 31);
        v8bf b = *(const v8bf*)(Wlds + brow * 128 + (kbyte ^ ((brow & 7) << 4)));
        acc[nf] = __builtin_amdgcn_mfma_f32_32x32x16_bf16(a, b, acc[nf], 0, 0, 0);
      }
    }
    __syncthreads();
  }
  // epilogue: write bf16 KQV
#pragma unroll
  for (int nf = 0; nf < 3; nf++) {
#pragma unroll
    for (int r = 0; r < 16; r++) {
      int row = wm * 32 + (r & 3) + ((r >> 2) << 3) + ((lane >> 5) << 2);
      int col = wn * 96 + nf * 32 + (lane & 31);
      KQV[(size_t)(row0 + row) * 192 + col] = (__bf16)acc[nf][r];
    }
  }
}

// ---------------------------------------------------------------------------
// Kernel 2: causal attention per batch. 256 blocks (= 128 batches x 2 halves)
// x 256 threads (4 waves). Wave owns 32 q-rows. Swapped QK^T -> lane-local softmax.
// ---------------------------------------------------------------------------
__launch_bounds__(256, 1)
__global__ void attn_kernel(const __bf16* __restrict__ KQV, float* __restrict__ out) {
  __shared__ uint4 lds4[81920 / 16];  // K:[256][64] 32KB | Vt:[64][256] 32KB | Q:[128][64] 16KB
  char* Klds = (char*)lds4;
  char* Vlds = (char*)lds4 + 32768;
  char* Qlds = (char*)lds4 + 65536;

  const int tid = threadIdx.x;
  const int lane = tid & 63;
  const int wave = tid >> 6;  // 0..3
  const int b = blockIdx.x >> 1;
  const int half = blockIdx.x & 1;
  const int bt0 = half * 128;
  const size_t base = (size_t)b * 256 * 192;

  // stage K rows (cols 64..127), swizzled row-major [s][h]
  {
    int s = tid;
    const uint4* src = (const uint4*)(KQV + base + (size_t)s * 192 + 64);
#pragma unroll
    for (int i = 0; i < 8; i++) {
      uint4 v = src[i];
      int byte = s * 128 + ((i * 16) ^ ((s & 7) << 4));
      *(uint4*)(Klds + byte) = v;
    }
  }
  // stage V transposed: Vt[h][s], swizzled (scatter b16 writes)
  {
    int s = tid;
    const uint4* src = (const uint4*)(KQV + base + (size_t)s * 192 + 128);
#pragma unroll
    for (int i = 0; i < 8; i++) {
      uint4 v = src[i];
      const ushort* e = (const ushort*)&v;
#pragma unroll
      for (int j = 0; j < 8; j++) {
        int h = i * 8 + j;
        int byte = h * 512 + ((s * 2) ^ ((h & 7) << 4));
        *(ushort*)(Vlds + byte) = e[j];
      }
    }
  }
  // stage Q rows (block's 128 t-rows, cols 0..63)
#pragma unroll
  for (int i = 0; i < 4; i++) {
    int c = tid + i * 256;
    int r = c >> 3, cc = c & 7;
    uint4 v = *(const uint4*)(KQV + base + (size_t)(bt0 + r) * 192 + cc * 8);
    int byte = r * 128 + ((cc * 16) ^ ((r & 7) << 4));
    *(uint4*)(Qlds + byte) = v;
  }
  __syncthreads();

  const int t0 = bt0 + wave * 32;
  const int tg = t0 + (lane & 31);   // this lane's q row
  const int nf = (t0 >> 5) + 1;      // causal: s frags needed

  // S^T = K * Q^T : D[s][t], col = t (lane-local q-row)
  f32x16 sacc[8];
#pragma unroll
  for (int sf = 0; sf < 8; sf++) {
    f32x16 sv = zero16();
    if (sf < nf) {
#pragma unroll
      for (int ks = 0; ks < 4; ks++) {
        int kbyte = ks * 32 + ((lane >> 5) << 4);
        int krow = sf * 32 + (lane & 31);
        v8bf a = *(const v8bf*)(Klds + krow * 128 + (kbyte ^ ((krow & 7) << 4)));
        int qrow = wave * 32 + (lane & 31);
        v8bf bq = *(const v8bf*)(Qlds + qrow * 128 + (kbyte ^ ((qrow & 7) << 4)));
        sv = __builtin_amdgcn_mfma_f32_32x32x16_bf16(a, bq, sv, 0, 0, 0);
      }
    }
    sacc[sf] = sv;
  }

  // scale + causal mask + row max (per-lane, rows are lane-local in t)
  float m = -1e30f;
#pragma unroll
  for (int sf = 0; sf < 8; sf++) {
    if (sf < nf) {
#pragma unroll
      for (int r = 0; r < 16; r++) {
        int sg = sf * 32 + (r & 3) + ((r >> 2) << 3) + ((lane >> 5) << 2);
        float v = sacc[sf][r] * 0.125f;
        v = (sg > tg) ? -1e30f : v;
        sacc[sf][r] = v;
        m = fmaxf(m, v);
      }
    }
  }
  m = fmaxf(m, __shfl_xor(m, 32, 64));
  float l = 0.f;
#pragma unroll
  for (int sf = 0; sf < 8; sf++) {
    if (sf < nf) {
#pragma unroll
      for (int r = 0; r < 16; r++) {
        float p = __expf(sacc[sf][r] - m);
        sacc[sf][r] = p;
        l += p;
      }
    }
  }
  l += __shfl_xor(l, 32, 64);
  float inv = 1.0f / l;

  // O = P * V : P as A-operand (built in-register via packed bf16 + shfl_xor 32)
  f32x16 oacc[2];
  oacc[0] = zero16();
  oacc[1] = zero16();
  const bool hiLane = (lane >= 32);
#pragma unroll
  for (int sf = 0; sf < 8; sf++) {
    if (sf < nf) {
      uint w[8], ow[8];
#pragma unroll
      for (int q = 0; q < 4; q++) {
        w[2 * q]     = pack_bf16(sacc[sf][4 * q] * inv,     sacc[sf][4 * q + 1] * inv);
        w[2 * q + 1] = pack_bf16(sacc[sf][4 * q + 2] * inv, sacc[sf][4 * q + 3] * inv);
      }
#pragma unroll
      for (int i = 0; i < 8; i++) ow[i] = (uint)__shfl_xor((int)w[i], 32, 64);
#pragma unroll
      for (int ks = 0; ks < 2; ks++) {
        int bse = 4 * ks;
        union { uint u[4]; v8bf v; } A;
        A.u[0] = hiLane ? ow[bse + 2] : w[bse + 0];
        A.u[1] = hiLane ? ow[bse + 3] : w[bse + 1];
        A.u[2] = hiLane ? w[bse + 2] : ow[bse + 0];
        A.u[3] = hiLane ? w[bse + 3] : ow[bse + 1];
        int sbyte0 = (sf * 32 + ks * 16) * 2 + ((lane >> 5) << 4);
#pragma unroll
        for (int hf = 0; hf < 2; hf++) {
          int vrow = hf * 32 + (lane & 31);
          v8bf bv = *(const v8bf*)(Vlds + vrow * 512 + (sbyte0 ^ ((vrow & 7) << 4)));
          oacc[hf] = __builtin_amdgcn_mfma_f32_32x32x16_bf16(A.v, bv, oacc[hf], 0, 0, 0);
        }
      }
    }
  }

  // write out fp32: D col = h, row pattern = t
#pragma unroll
  for (int hf = 0; hf < 2; hf++) {
#pragma unroll
    for (int r = 0; r < 16; r++) {
      int t = t0 + (r & 3) + ((r >> 2) << 3) + ((lane >> 5) << 2);
      int h = hf * 32 + (lane & 31);
      out[((size_t)b * 256 + t) * 64 + h] = oacc[hf][r];
    }
  }
}

// ---------------------------------------------------------------------------
extern "C" void kernel_launch(void* const* d_in, const int* in_sizes, int n_in,
                              void* d_out, int out_size, void* d_ws, size_t ws_size,
                              hipStream_t stream) {
  const float* x  = (const float*)d_in[0];
  const float* Wk = (const float*)d_in[1];
  const float* Wq = (const float*)d_in[2];
  const float* Wv = (const float*)d_in[3];
  float* out = (float*)d_out;

  // workspace layout: KQV bf16 [32768][192] (12.58 MB), then Wt bf16 [192][1024]
  __bf16* KQV = (__bf16*)d_ws;
  __bf16* Wt  = (__bf16*)((char*)d_ws + (size_t)32768 * 192 * 2);

  prep_wt<<<192, 256, 0, stream>>>(Wq, Wk, Wv, Wt);
  proj_kernel<<<256, 512, 0, stream>>>(x, (const uint4*)Wt, KQV);
  attn_kernel<<<256, 256, 0, stream>>>(KQV, out);
}